// Round 5
// baseline (5854.519 us; speedup 1.0000x reference)
//
#include <hip/hip_runtime.h>
#include <hip/hip_bf16.h>
#include <math.h>

// ---------------------------------------------------------------------------
// Show-Attend-Tell LSTM decoder, round 5.
// Round 4 failed: cooperative launch produced no work (preds==0 => absmax ==
// max|ref|). Same persistent-loop structure, but grid sync is now a
// hand-rolled device-scope barrier (one slot per sync, ACQ_REL/AGENT atomics)
// in a PLAIN kernel launch: no cooperative API, graph-capture safe.
// 256 blocks x 256 thr = 1 block/CU, trivially co-resident.
// ---------------------------------------------------------------------------

#define BB 64
#define PP 196
#define EE 2048
#define AA 512
#define DD 512
#define VV 10000
#define TT 20
#define XX 2560          // E_EMB(512) + E_ENC(2048)
#define NZ 4608          // att2(512) + gatepre(2048) + gates_hh(2048)
#define S1S 2
#define S4S 8
#define NBLK 256

typedef __attribute__((ext_vector_type(8))) short bf16x8;
typedef __attribute__((ext_vector_type(4))) float f32x4;

__device__ __forceinline__ unsigned short f2b(float f) {
  unsigned int x = __float_as_uint(f);
  x += 0x7fff + ((x >> 16) & 1);          // RNE
  return (unsigned short)(x >> 16);
}
__device__ __forceinline__ float b2f(unsigned short u) {
  return __uint_as_float(((unsigned int)u) << 16);
}
__device__ __forceinline__ void gload16(const void* g, void* l) {
  __builtin_amdgcn_global_load_lds(
      (const __attribute__((address_space(1))) unsigned int*)g,
      (__attribute__((address_space(3))) unsigned int*)l, 16, 0, 0);
}

// device-scope grid barrier; slot `idx` used exactly once per kernel call.
__device__ __forceinline__ void gridbar(unsigned int* bar, int idx, int tid) {
  __syncthreads();
  if (tid == 0) {
    __hip_atomic_fetch_add(&bar[idx], 1u, __ATOMIC_ACQ_REL,
                           __HIP_MEMORY_SCOPE_AGENT);
    while (__hip_atomic_load(&bar[idx], __ATOMIC_ACQUIRE,
                             __HIP_MEMORY_SCOPE_AGENT) < (unsigned)NBLK) {
      __builtin_amdgcn_s_sleep(2);
    }
  }
  __syncthreads();
}

// -------------------------------- preamble ---------------------------------

__global__ void k_order(const int* __restrict__ cap_len,
                        int* __restrict__ order, int* __restrict__ declen,
                        unsigned int* __restrict__ bar) {
  int i = threadIdx.x;
  for (int j = i; j < 128; j += 64) bar[j] = 0;   // zero barrier slots
  __shared__ int len[BB];
  len[i] = cap_len[i];
  __syncthreads();
  int key = (64 - len[i]) * 64 + i;      // descending len, stable
  int rank = 0;
  for (int j = 0; j < BB; ++j) {
    int kj = (64 - len[j]) * 64 + j;
    rank += (kj < key);
  }
  order[rank] = i;
  declen[rank] = len[i] - 1;
}

// gather-sort encoder to bf16 + bf16 mean
__global__ __launch_bounds__(256) void k_enc_conv(
    const float* __restrict__ enc, const int* __restrict__ order,
    unsigned short* __restrict__ enc_s, unsigned short* __restrict__ meanb) {
  const int b = blockIdx.x;
  const int e = blockIdx.y * 256 + threadIdx.x;
  const float* src = enc + ((size_t)order[b] * PP) * EE + e;
  unsigned short* dst = enc_s + ((size_t)b * PP) * EE + e;
  float s = 0.f;
#pragma unroll 4
  for (int p = 0; p < PP; ++p) {
    float v = src[(size_t)p * EE];
    s += v;
    dst[(size_t)p * EE] = f2b(v);
  }
  meanb[(size_t)b * EE + e] = f2b(s * (1.0f / PP));
}

// bulk f32 -> bf16 (8 elems / thread)
__global__ __launch_bounds__(256) void k_f2b8(const float* __restrict__ src,
                                              unsigned short* __restrict__ dst,
                                              int n8) {
  int i = blockIdx.x * 256 + threadIdx.x;
  if (i >= n8) return;
  float4 a = ((const float4*)src)[2 * i];
  float4 c = ((const float4*)src)[2 * i + 1];
  union { unsigned short u[8]; uint4 v; } o;
  o.u[0] = f2b(a.x); o.u[1] = f2b(a.y); o.u[2] = f2b(a.z); o.u[3] = f2b(a.w);
  o.u[4] = f2b(c.x); o.u[5] = f2b(c.y); o.u[6] = f2b(c.z); o.u[7] = f2b(c.w);
  ((uint4*)dst)[i] = o.v;
}

// combine Hp partials -> h0 (bf16) and c0 (fp32)
__global__ __launch_bounds__(256) void k_h0c0_fin(
    const float* __restrict__ Hp, const float* __restrict__ hb,
    const float* __restrict__ cb, unsigned short* __restrict__ h0,
    float* __restrict__ c0) {
  const int idx = blockIdx.x * 256 + threadIdx.x;   // 0..65535
  const int b = idx >> 10, n = idx & 1023;
  float s = 0.f;
#pragma unroll
  for (int sp = 0; sp < 8; ++sp)
    s += Hp[((size_t)sp * BB + b) * 1024 + n];
  if (n < DD) h0[(size_t)b * DD + n] = f2b(s + hb[n]);
  else        c0[(size_t)b * DD + (n - DD)] = s + cb[n - DD];
}

// ------------------------- big MFMA GEMM (128x128) -------------------------
template <int EPI>
__global__ __launch_bounds__(256) void k_gemm_big(
    const unsigned short* __restrict__ A, const unsigned short* __restrict__ B,
    int K, int nt, unsigned short* __restrict__ outb,
    float* __restrict__ outf, const float* __restrict__ bias,
    const int* __restrict__ declen) {
  __shared__ __align__(16) char smem[2][16384];   // A 8KB + B 8KB per buffer
  const int tid = threadIdx.x;
  const int l = tid & 63;
  const int w = tid >> 6;
  const int wr = w >> 1, wc = w & 1;
  const int m0 = blockIdx.x * 128;
  const int n0 = blockIdx.y * 128;
  f32x4 acc[4][4] = {};

  const int srr = l >> 2;     // row-in-chunk 0..15
  const int ssl = l & 3;      // physical 16B slot
  auto stage = [&](int t) {
    char* dst = &smem[t & 1][0];
    const int k0 = t * 32;
#pragma unroll
    for (int q = 0; q < 4; ++q) {
      const int c = w * 4 + q;               // chunk 0..15 (1 KiB each)
      const int rr = (c & 7) * 16 + srr;     // tile row / col 0..127
      const int sg = ssl ^ ((rr >> 1) & 3);  // logical k-slot for this slot
      const unsigned short* src;
      if (c < 8) {
        src = A + (size_t)(m0 + rr) * K + k0 + sg * 8;
      } else {
        int gc = n0 + rr;
        if (EPI == 1 && gc >= VV) gc = 0;    // clamp OOB weight rows
        src = B + (size_t)gc * K + k0 + sg * 8;
      }
      gload16(src, dst + c * 1024);
    }
  };

  stage(0);
  __syncthreads();
  const int ks = l >> 4;
  for (int t = 0; t < nt; ++t) {
    if (t + 1 < nt) stage(t + 1);
    const char* sa = &smem[t & 1][0];
    const char* sbp = sa + 8192;
    bf16x8 ar[4], br[4];
#pragma unroll
    for (int f = 0; f < 4; ++f) {
      const int row = wr * 64 + f * 16 + (l & 15);
      ar[f] = *(const bf16x8*)(sa + row * 64 + ((ks ^ ((row >> 1) & 3)) << 4));
      const int col = wc * 64 + f * 16 + (l & 15);
      br[f] = *(const bf16x8*)(sbp + col * 64 + ((ks ^ ((col >> 1) & 3)) << 4));
    }
#pragma unroll
    for (int fi = 0; fi < 4; ++fi)
#pragma unroll
      for (int fj = 0; fj < 4; ++fj)
        acc[fi][fj] = __builtin_amdgcn_mfma_f32_16x16x32_bf16(
            ar[fi], br[fj], acc[fi][fj], 0, 0, 0);
    __syncthreads();
  }
#pragma unroll
  for (int fi = 0; fi < 4; ++fi) {
    const int grow = m0 + wr * 64 + fi * 16 + (l >> 4) * 4;
#pragma unroll
    for (int fj = 0; fj < 4; ++fj) {
      const int gcol = n0 + wc * 64 + fj * 16 + (l & 15);
      if (EPI == 0) {
        const float bv = bias[gcol];
#pragma unroll
        for (int r = 0; r < 4; ++r)
          outb[(size_t)(grow + r) * AA + gcol] = f2b(acc[fi][fj][r] + bv);
      } else {
        if (gcol < VV) {
          const float bv = bias[gcol];
#pragma unroll
          for (int r = 0; r < 4; ++r) {
            const int m = grow + r;
            const int t_ = m >> 6, b_ = m & 63;
            const float v = (t_ < declen[b_]) ? acc[fi][fj][r] + bv : 0.f;
            outf[((size_t)b_ * TT + t_) * VV + gcol] = v;
          }
        }
      }
    }
  }
}

// ------------------- skinny 64x64 MFMA tile (device fn) --------------------
__device__ __forceinline__ void skinny_tile(
    const unsigned short* A, int lda, const unsigned short* B, int ldb,
    int n0, int kb, int nt, float* out, int ldo, char* smem, int tid) {
  const int l = tid & 63;
  const int w = tid >> 6;
  f32x4 acc[4] = {};
  const int srr = l >> 2, ssl = l & 3;
  auto stage = [&](int t2) {
    char* dst = smem + (t2 & 1) * 8192;
    const int k0 = kb + t2 * 32;
#pragma unroll
    for (int q = 0; q < 2; ++q) {
      const int c = w * 2 + q;               // chunk 0..7
      const int rr = (c & 3) * 16 + srr;     // 0..63
      const int sg = ssl ^ ((rr >> 1) & 3);
      const unsigned short* src = (c < 4)
          ? A + (size_t)rr * lda + k0 + sg * 8
          : B + (size_t)(n0 + rr) * ldb + k0 + sg * 8;
      gload16(src, dst + c * 1024);
    }
  };
  stage(0);
  __syncthreads();
  const int ks = l >> 4;
  for (int t2 = 0; t2 < nt; ++t2) {
    if (t2 + 1 < nt) stage(t2 + 1);
    const char* sa = smem + (t2 & 1) * 8192;
    bf16x8 ar[4];
#pragma unroll
    for (int f = 0; f < 4; ++f) {
      const int row = f * 16 + (l & 15);
      ar[f] = *(const bf16x8*)(sa + row * 64 + ((ks ^ ((row >> 1) & 3)) << 4));
    }
    const int col = w * 16 + (l & 15);
    bf16x8 br = *(const bf16x8*)(sa + 4096 + col * 64 +
                                 ((ks ^ ((col >> 1) & 3)) << 4));
#pragma unroll
    for (int f = 0; f < 4; ++f)
      acc[f] = __builtin_amdgcn_mfma_f32_16x16x32_bf16(ar[f], br, acc[f],
                                                       0, 0, 0);
    __syncthreads();
  }
  const int gcol = n0 + w * 16 + (l & 15);
#pragma unroll
  for (int f = 0; f < 4; ++f) {
    const int grow = f * 16 + (l >> 4) * 4;
#pragma unroll
    for (int r = 0; r < 4; ++r)
      out[(size_t)(grow + r) * ldo + gcol] = acc[f][r];
  }
}

// skinny GEMM as standalone kernel (used for h0/c0 in preamble)
__global__ __launch_bounds__(256) void k_skinny(
    const unsigned short* __restrict__ A, int lda,
    const unsigned short* __restrict__ B, int ldb, int kspan, int nt,
    float* __restrict__ out, int ldo, long sstride) {
  __shared__ __align__(16) char smem[16384];
  skinny_tile(A, lda, B, ldb, blockIdx.x * 64, blockIdx.y * kspan, nt,
              out + (size_t)blockIdx.y * sstride, ldo, smem, threadIdx.x);
}

// --------------------- persistent loop (plain launch) ----------------------

__global__ __launch_bounds__(256) void k_loop(
    unsigned short* h_all, unsigned short* x, float* Zp, float* Gp,
    float* cbuf, float* alph, const unsigned short* eatt,
    const unsigned short* enc_s, const unsigned short* Wzb,
    const unsigned short* Wihb, const float* adb, const float* afW,
    const float* afb, const float* sb, const float* embW, const float* bih,
    const float* bhh, const int* cap, const int* order, const int* declen,
    float* alphas, unsigned int* bar) {
  const int blk = blockIdx.x;
  const int tid = threadIdx.x;
  __shared__ __align__(16) char smem[16384];
  int bidx = 0;

#pragma unroll 1
  for (int t = 0; t < TT; ++t) {
    // ---- phase 1: S1  Zp[2][64][4608] = h_t @ [adW|sW|Whh]^T, K=512 ------
    if (blk < 144) {
      const int split = blk / 72, ntile = blk % 72;
      skinny_tile(h_all + (size_t)t * BB * DD, 512, Wzb, 512, ntile * 64,
                  split * 256, 8, Zp + (size_t)split * BB * NZ, NZ, smem, tid);
    }
    gridbar(bar, bidx++, tid);

    // ---- phase 2: att scores + softmax (blocks 0..63, b = blk) ----------
    if (blk < BB) {
      const int b = blk;
      float* att2 = (float*)smem;          // 512
      float* wf = att2 + 512;              // 512
      float* esm = wf + 512;               // 200
      float* red = esm + 200;              // 16
      for (int a = tid; a < AA; a += 256) {
        att2[a] = Zp[(size_t)b * NZ + a] + Zp[((size_t)BB + b) * NZ + a] +
                  adb[a];
        wf[a] = afW[a];
      }
      __syncthreads();
      const int lane = tid & 63;
      const int w = tid >> 6;              // 0..3
      for (int p = w; p < PP; p += 4) {
        uint4 v =
            *(const uint4*)(eatt + ((size_t)(b * PP + p)) * AA + lane * 8);
        const float* a2 = &att2[lane * 8];
        const float* wv = &wf[lane * 8];
        unsigned int uu[4] = {v.x, v.y, v.z, v.w};
        float s = 0.f;
#pragma unroll
        for (int j = 0; j < 4; ++j) {
          float e0 = b2f((unsigned short)(uu[j] & 0xffffu));
          float e1 = b2f((unsigned short)(uu[j] >> 16));
          float u0 = e0 + a2[2 * j];     u0 = u0 > 0.f ? u0 : 0.f;
          float u1 = e1 + a2[2 * j + 1]; u1 = u1 > 0.f ? u1 : 0.f;
          s += u0 * wv[2 * j] + u1 * wv[2 * j + 1];
        }
#pragma unroll
        for (int off = 32; off; off >>= 1) s += __shfl_xor(s, off);
        if (lane == 0) esm[p] = s + afb[0];
      }
      __syncthreads();
      float v = (tid < PP) ? esm[tid] : -3.4e38f;
      float m = v;
#pragma unroll
      for (int off = 32; off; off >>= 1) m = fmaxf(m, __shfl_xor(m, off));
      if (lane == 0) red[w] = m;
      __syncthreads();
      m = fmaxf(fmaxf(red[0], red[1]), fmaxf(red[2], red[3]));
      float ex = (tid < PP) ? __expf(v - m) : 0.f;
      float ssum = ex;
#pragma unroll
      for (int off = 32; off; off >>= 1) ssum += __shfl_xor(ssum, off);
      if (lane == 0) red[8 + w] = ssum;
      __syncthreads();
      float tot = red[8] + red[9] + red[10] + red[11];
      if (tid < PP) {
        float a_ = ex / tot;
        alph[(size_t)b * PP + tid] = a_;
        alphas[((size_t)b * TT + t) * PP + tid] =
            (t < declen[b]) ? a_ : 0.f;
      }
    }
    gridbar(bar, bidx++, tid);

    // ---- phase 3: ctx + gate + x assembly (256 blocks) ------------------
    {
      const int b = blk >> 2, q = blk & 3;
      const int rg = tid >> 6, lt = tid & 63;
      float* al_s = (float*)smem;          // 200 (+pad)
      float* part = al_s + 256;            // 2048
      for (int p = tid; p < PP; p += 256) al_s[p] = alph[(size_t)b * PP + p];
      __syncthreads();
      const int e0 = q * 512 + lt * 8;
      float acc[8] = {};
      const unsigned short* ep = enc_s + ((size_t)b * PP) * EE + e0;
      for (int p = rg; p < PP; p += 4) {
        uint4 vv = *(const uint4*)(ep + (size_t)p * EE);
        const float ap = al_s[p];
        unsigned int uu[4] = {vv.x, vv.y, vv.z, vv.w};
#pragma unroll
        for (int j = 0; j < 4; ++j) {
          acc[2 * j]     += ap * b2f((unsigned short)(uu[j] & 0xffffu));
          acc[2 * j + 1] += ap * b2f((unsigned short)(uu[j] >> 16));
        }
      }
#pragma unroll
      for (int j = 0; j < 8; ++j) part[(rg * 64 + lt) * 8 + j] = acc[j];
      __syncthreads();
      if (tid < 64) {
        const int e = q * 512 + tid * 8;
        float s8[8];
#pragma unroll
        for (int j = 0; j < 8; ++j)
          s8[j] = part[(0 * 64 + tid) * 8 + j] + part[(1 * 64 + tid) * 8 + j] +
                  part[(2 * 64 + tid) * 8 + j] + part[(3 * 64 + tid) * 8 + j];
        const float* zg0 = Zp + (size_t)b * NZ + AA + e;
        const float* zg1 = Zp + ((size_t)BB + b) * NZ + AA + e;
        float4 z0a = *(const float4*)zg0, z0b = *(const float4*)(zg0 + 4);
        float4 z1a = *(const float4*)zg1, z1b = *(const float4*)(zg1 + 4);
        float4 sa = *(const float4*)(sb + e), sbv = *(const float4*)(sb + e + 4);
        float gz[8] = {z0a.x + z1a.x + sa.x,  z0a.y + z1a.y + sa.y,
                       z0a.z + z1a.z + sa.z,  z0a.w + z1a.w + sa.w,
                       z0b.x + z1b.x + sbv.x, z0b.y + z1b.y + sbv.y,
                       z0b.z + z1b.z + sbv.z, z0b.w + z1b.w + sbv.w};
        union { unsigned short u[8]; uint4 v; } o;
#pragma unroll
        for (int j = 0; j < 8; ++j) {
          float g = 1.f / (1.f + __expf(-gz[j]));
          o.u[j] = f2b(g * s8[j]);
        }
        *(uint4*)(x + (size_t)b * XX + AA + e) = o.v;
      } else if (q == 0 && tid < 128) {
        const int lt2 = tid - 64;
        const int tok = cap[order[b] * 21 + t];
        const int e = lt2 * 8;
        const float* es = embW + (size_t)tok * 512 + e;
        float4 a0 = *(const float4*)es, a1 = *(const float4*)(es + 4);
        union { unsigned short u[8]; uint4 v; } m_;
        m_.u[0] = f2b(a0.x); m_.u[1] = f2b(a0.y);
        m_.u[2] = f2b(a0.z); m_.u[3] = f2b(a0.w);
        m_.u[4] = f2b(a1.x); m_.u[5] = f2b(a1.y);
        m_.u[6] = f2b(a1.z); m_.u[7] = f2b(a1.w);
        *(uint4*)(x + (size_t)b * XX + e) = m_.v;
      }
    }
    gridbar(bar, bidx++, tid);

    // ---- phase 4: S4  Gp[8][64][2048] = x @ Wih^T, K=2560 splitK 8 ------
    {
      const int ntile = blk & 31, split = blk >> 5;
      skinny_tile(x, XX, Wihb, XX, ntile * 64, split * 320, 10,
                  Gp + (size_t)split * BB * 2048, 2048, smem, tid);
    }
    gridbar(bar, bidx++, tid);

    // ---- phase 5: LSTM cell (blocks 0..127) -----------------------------
    if (blk < 128) {
      const int idx = blk * 256 + tid;     // b*512 + d
      const int b = idx >> 9, d = idx & 511;
      float g4[4];
#pragma unroll
      for (int q = 0; q < 4; ++q) {
        const int j = q * 512 + d;
        float s = bih[j] + bhh[j] + Zp[(size_t)b * NZ + 2560 + j] +
                  Zp[((size_t)BB + b) * NZ + 2560 + j];
#pragma unroll
        for (int sp = 0; sp < S4S; ++sp)
          s += Gp[((size_t)sp * BB + b) * 2048 + j];
        g4[q] = s;
      }
      const float ig = 1.f / (1.f + __expf(-g4[0]));
      const float fg = 1.f / (1.f + __expf(-g4[1]));
      const float gg = tanhf(g4[2]);
      const float og = 1.f / (1.f + __expf(-g4[3]));
      const float c = fg * cbuf[(size_t)(t & 1) * BB * DD + idx] + ig * gg;
      const float h = og * tanhf(c);
      cbuf[(size_t)((t + 1) & 1) * BB * DD + idx] = c;
      h_all[(size_t)(t + 1) * BB * DD + idx] = f2b(h);
    }
    gridbar(bar, bidx++, tid);
  }
}

// ------------------------------ launch -------------------------------------

extern "C" void kernel_launch(void* const* d_in, const int* in_sizes, int n_in,
                              void* d_out, int out_size, void* d_ws,
                              size_t ws_size, hipStream_t stream) {
  (void)in_sizes; (void)n_in; (void)out_size; (void)ws_size;
  const float* enc  = (const float*)d_in[0];
  const float* embW = (const float*)d_in[1];
  const float* hW   = (const float*)d_in[2];
  const float* hb   = (const float*)d_in[3];
  const float* cW   = (const float*)d_in[4];
  const float* cb   = (const float*)d_in[5];
  const float* aeW  = (const float*)d_in[6];
  const float* aeb  = (const float*)d_in[7];
  const float* adW  = (const float*)d_in[8];
  const float* adb  = (const float*)d_in[9];
  const float* afW  = (const float*)d_in[10];
  const float* afb  = (const float*)d_in[11];
  const float* sW   = (const float*)d_in[12];
  const float* sb   = (const float*)d_in[13];
  const float* Wih  = (const float*)d_in[14];
  const float* Whh  = (const float*)d_in[15];
  const float* bih  = (const float*)d_in[16];
  const float* bhh  = (const float*)d_in[17];
  const float* fcW  = (const float*)d_in[18];
  const float* fcb  = (const float*)d_in[19];
  const int*   cap  = (const int*)d_in[20];
  const int*   capl = (const int*)d_in[21];

  char* p = (char*)d_ws;
  int* order  = (int*)p;            p += 256;
  int* declen = (int*)p;            p += 256;
  unsigned int* bar = (unsigned int*)p; p += 512;   // 128 slots
  float* cbuf = (float*)p;          p += 2 * (size_t)BB * DD * 4;      // 256 KB
  float* Zp   = (float*)p;          p += (size_t)S1S * BB * NZ * 4;    // 2.4 MB
  float* Gp   = (float*)p;          p += (size_t)S4S * BB * 2048 * 4;  // 4 MB
  float* Hp   = (float*)p;          p += (size_t)8 * BB * 1024 * 4;    // 2 MB
  float* alph = (float*)p;          p += (size_t)BB * PP * 4;          // 50 KB
  unsigned short* meanb = (unsigned short*)p; p += (size_t)BB * EE * 2;
  unsigned short* x     = (unsigned short*)p; p += (size_t)BB * XX * 2;
  unsigned short* h_all = (unsigned short*)p; p += (size_t)(TT + 1) * BB * DD * 2;
  unsigned short* aeWb  = (unsigned short*)p; p += (size_t)AA * EE * 2;
  unsigned short* Wzb   = (unsigned short*)p; p += (size_t)NZ * DD * 2;
  unsigned short* Whcb  = (unsigned short*)p; p += (size_t)1024 * EE * 2;
  unsigned short* Wihb  = (unsigned short*)p; p += (size_t)2048 * XX * 2;
  unsigned short* fcWb  = (unsigned short*)p; p += (size_t)VV * DD * 2;
  unsigned short* eattb = (unsigned short*)p; p += (size_t)BB * PP * AA * 2;
  unsigned short* enc_s = (unsigned short*)p; p += (size_t)BB * PP * EE * 2;
  // total ws ~103 MB

  float* preds  = (float*)d_out;                        // [64][20][10000]
  float* alphas = preds + (size_t)BB * TT * VV;         // [64][20][196]

  k_order<<<1, 64, 0, stream>>>(capl, order, declen, bar);
  k_enc_conv<<<dim3(BB, EE / 256), 256, 0, stream>>>(enc, order, enc_s, meanb);
  k_f2b8<<<512,  256, 0, stream>>>(aeW, aeWb, AA * EE / 8);
  k_f2b8<<<128,  256, 0, stream>>>(adW, Wzb, 512 * 512 / 8);
  k_f2b8<<<512,  256, 0, stream>>>(sW,  Wzb + 512 * 512, 2048 * 512 / 8);
  k_f2b8<<<512,  256, 0, stream>>>(Whh, Wzb + 2560 * 512, 2048 * 512 / 8);
  k_f2b8<<<512,  256, 0, stream>>>(hW,  Whcb, 512 * EE / 8);
  k_f2b8<<<512,  256, 0, stream>>>(cW,  Whcb + 512 * EE, 512 * EE / 8);
  k_f2b8<<<2560, 256, 0, stream>>>(Wih, Wihb, 2048 * XX / 8);
  k_f2b8<<<2500, 256, 0, stream>>>(fcW, fcWb, VV * 512 / 8);
  // h0/c0: [64][1024] = meanb @ [hW;cW]^T, K=2048, 8 splits
  k_skinny<<<dim3(1024 / 64, 8), 256, 0, stream>>>(
      meanb, EE, Whcb, EE, 256, 8, Hp, 1024, (long)BB * 1024);
  k_h0c0_fin<<<256, 256, 0, stream>>>(Hp, hb, cb, h_all, cbuf);
  // enc_att: M=12544, N=512, K=2048
  k_gemm_big<0><<<dim3((BB * PP) / 128, AA / 128), 256, 0, stream>>>(
      enc_s, aeWb, EE, EE / 32, eattb, nullptr, aeb, nullptr);

  // the whole 20-step decode loop: one persistent kernel, plain launch
  k_loop<<<NBLK, 256, 0, stream>>>(h_all, x, Zp, Gp, cbuf, alph, eattb, enc_s,
                                   Wzb, Wihb, adb, afW, afb, sb, embW, bih,
                                   bhh, cap, order, declen, alphas, bar);

  // preds: M=1280 (=20*64 h states), N=10000, K=512
  k_gemm_big<1><<<dim3(10, 79), 256, 0, stream>>>(
      h_all + (size_t)BB * DD, fcWb, 512, 16, nullptr, preds, fcb, declen);
}